// Round 4
// baseline (90533.362 us; speedup 1.0000x reference)
//
#include <hip/hip_runtime.h>
#include <hip/hip_bf16.h>

// ---------------------------------------------------------------------------
// Round 4: correctness-first, zero-MFMA, dtype-adaptive.
//   k_detect : decide fp32 vs bf16 input buffers by bit-pattern statistics
//   k_cvt    : canonicalize all 23 parameter tensors -> bf16 ws copies
//   k_build  : features (98304 x 256) -> ws bf16
//   k_rowmm  : out = A(ws bf16) @ W(ws bf16).T + bias   (wi and wd_mid)
//   k_encoder: pure-VALU recurrence, 64 blocks x 512 thr x 16 batch rows
//   k_decoder: scalar-hidden LSTM, 1024 blocks x 16 steps
// ---------------------------------------------------------------------------

typedef unsigned short ushort_t;

#define DEVFN static __device__ __forceinline__

DEVFN float bs2f(ushort_t u) {
    union { float f; unsigned v; } c; c.v = ((unsigned)u) << 16; return c.f;
}
DEVFN ushort_t f2bs(float f) {
    __hip_bfloat16 h = __float2bfloat16(f);
    return *reinterpret_cast<ushort_t*>(&h);
}
DEVFN float gload(const void* p, long i, int bf) {
    if (bf) return bs2f(((const ushort_t*)p)[i]);
    return ((const float*)p)[i];
}
DEVFN float sigm(float x) { return 1.f / (1.f + __expf(-x)); }
DEVFN float ftanh(float x) {
    float t = __expf(-2.f * fabsf(x));
    float r = (1.f - t) / (1.f + t);
    return copysignf(r, x);
}

// ---- parameter tensors copied into ws as bf16 -----------------------------
struct SrcPtrs { const void* p[26]; };
struct WsPtrs {
    ushort_t *wcfg, *bcfg, *eh, *ew, *es, *wis, *bis, *wes, *vds, *bvds,
             *whh, *wih, *bih, *bhh, *wdt, *bdt, *wd2t, *vdt, *bvdt,
             *wihd, *whhd, *bihd, *bhhd;
};

// ---------------------------------------------------------------------------
// k_detect: flag=1 iff probe buffer looks like bf16. Checks the low ushort of
// the first 16 32-bit words: genuine bf16 N(0,0.05^2) values always have
// exponent in [96,126] (or are 0); fp32 low-mantissa halves are ~uniform
// (P(pass all 16) ~ 4e-15).
// ---------------------------------------------------------------------------
__global__ void k_detect(const void* probe, int* flag) {
    if (threadIdx.x == 0 && blockIdx.x == 0) {
        const ushort_t* u = (const ushort_t*)probe;
        int ok = 1;
        for (int i = 0; i < 16; ++i) {
            ushort_t v = u[2 * i];
            int e = (v >> 7) & 0xFF;
            if (!(v == 0 || (e >= 96 && e <= 126))) ok = 0;
        }
        *flag = ok;
    }
}

// ---------------------------------------------------------------------------
// k_cvt: one block per parameter tensor; grid-stride copy src -> ws bf16.
// If src is already bf16, f2bs(bs2f(x)) == x (lossless).
// ---------------------------------------------------------------------------
__global__ __launch_bounds__(256) void k_cvt(SrcPtrs sp, WsPtrs wp, const int* flagp) {
    int bf = *flagp;
    const void* src = nullptr; ushort_t* dst = nullptr; long n = 0;
    switch (blockIdx.x) {
        case 0:  src = sp.p[3];  dst = wp.wcfg; n = 320;    break;
        case 1:  src = sp.p[4];  dst = wp.bcfg; n = 10;     break;
        case 2:  src = sp.p[5];  dst = wp.eh;   n = 120;    break;
        case 3:  src = sp.p[6];  dst = wp.ew;   n = 24;     break;
        case 4:  src = sp.p[7];  dst = wp.es;   n = 15;     break;
        case 5:  src = sp.p[16]; dst = wp.wis;  n = 65536;  break;
        case 6:  src = sp.p[17]; dst = wp.bis;  n = 256;    break;
        case 7:  src = sp.p[18]; dst = wp.wes;  n = 131072; break;
        case 8:  src = sp.p[19]; dst = wp.vds;  n = 256;    break;
        case 9:  src = sp.p[20]; dst = wp.bvds; n = 1;      break;
        case 10: src = sp.p[9];  dst = wp.whh;  n = 262144; break;
        case 11: src = sp.p[8];  dst = wp.wih;  n = 262144; break;
        case 12: src = sp.p[10]; dst = wp.bih;  n = 1024;   break;
        case 13: src = sp.p[11]; dst = wp.bhh;  n = 1024;   break;
        case 14: src = sp.p[21]; dst = wp.wdt;  n = 65536;  break;
        case 15: src = sp.p[22]; dst = wp.bdt;  n = 256;    break;
        case 16: src = sp.p[23]; dst = wp.wd2t; n = 512;    break;
        case 17: src = sp.p[24]; dst = wp.vdt;  n = 256;    break;
        case 18: src = sp.p[25]; dst = wp.bvdt; n = 1;      break;
        case 19: src = sp.p[12]; dst = wp.wihd; n = 1028;   break;
        case 20: src = sp.p[13]; dst = wp.whhd; n = 4;      break;
        case 21: src = sp.p[14]; dst = wp.bihd; n = 4;      break;
        case 22: src = sp.p[15]; dst = wp.bhhd; n = 4;      break;
        default: return;
    }
    for (long i = threadIdx.x; i < n; i += 256) {
        float v = bf ? bs2f(((const ushort_t*)src)[i]) : ((const float*)src)[i];
        dst[i] = f2bs(v);
    }
}

// ---------------------------------------------------------------------------
// k_build: features. 6144 blocks x 256 thr, 16 rows/block.
// layout: [0:235) p_q | [235:245) cfg@Wcfg.T+b | [245:250) hour | [250:253) wd
//         | [253:256) season
// ---------------------------------------------------------------------------
__global__ __launch_bounds__(256) void k_build(
    const void* __restrict__ pq, const void* __restrict__ cfg_in,
    const int* __restrict__ timei, WsPtrs wp, const int* __restrict__ flagp,
    ushort_t* __restrict__ inputs)
{
    int bf = *flagp;
    int ch = threadIdx.x;
    for (int rr = 0; rr < 16; ++rr) {
        long row = (long)blockIdx.x * 16 + rr;
        float v;
        if (ch < 235) {
            v = gload(pq, row * 235 + ch, bf);
        } else if (ch < 245) {
            int j = ch - 235;
            float acc = bs2f(wp.bcfg[j]);
            for (int k = 0; k < 32; ++k)
                acc += gload(cfg_in, row * 32 + k, bf) * bs2f(wp.wcfg[j * 32 + k]);
            v = acc;
        } else if (ch < 250) {
            v = bs2f(wp.eh[timei[row * 3 + 0] * 5 + (ch - 245)]);
        } else if (ch < 253) {
            v = bs2f(wp.ew[timei[row * 3 + 1] * 3 + (ch - 250)]);
        } else {
            v = bs2f(wp.es[timei[row * 3 + 2] * 3 + (ch - 253)]);
        }
        inputs[row * 256 + ch] = f2bs(v);
    }
}

// ---------------------------------------------------------------------------
// k_rowmm: out[r][n] = bias[n] + sum_k A[r][k]*W[n][k].  A,W,out ws bf16.
// 6144 blocks x 256 thr, 16 rows/block; thread owns col n=tid for all rows.
// ---------------------------------------------------------------------------
__global__ __launch_bounds__(256) void k_rowmm(
    const ushort_t* __restrict__ A, const ushort_t* __restrict__ W,
    const ushort_t* __restrict__ bias, ushort_t* __restrict__ out)
{
    __shared__ float At[16][257];
    int tid = threadIdx.x;
    long row0 = (long)blockIdx.x * 16;
    for (int r = 0; r < 16; ++r) At[r][tid] = bs2f(A[(row0 + r) * 256 + tid]);
    __syncthreads();
    float acc[16];
    float bv = bs2f(bias[tid]);
#pragma unroll
    for (int r = 0; r < 16; ++r) acc[r] = bv;
    const ushort_t* wr = W + (long)tid * 256;
    for (int k = 0; k < 256; ++k) {
        float wv = bs2f(wr[k]);
#pragma unroll
        for (int r = 0; r < 16; ++r) acc[r] += At[r][k] * wv;
    }
    for (int r = 0; r < 16; ++r) out[(row0 + r) * 256 + tid] = f2bs(acc[r]);
}

// ---------------------------------------------------------------------------
// k_encoder: 64 blocks x 512 thr, 16 batch rows/block, 96 steps, pure VALU.
// thread (r = tid>>5, j = tid&31). Per step:
//   stage x; sync; attn matvec (8 n/thread) -> half-wave shuffle reduce -> aL;
//   sync; gates matvec (8 u x 4 gates/thread, h and x dots) -> cell in regs;
//   sync; write back h,c; sync.
// ---------------------------------------------------------------------------
__global__ __launch_bounds__(512) void k_encoder(
    const ushort_t* __restrict__ wi, const ushort_t* __restrict__ inputs,
    WsPtrs wp, ushort_t* __restrict__ mid)
{
    __shared__ float hL[16][260];
    __shared__ float cL[16][260];
    __shared__ float xL[16][260];
    __shared__ float bcombL[1024];
    __shared__ float aL[16];

    int tid = threadIdx.x;
    int r = tid >> 5, j = tid & 31;
    long row0 = (long)blockIdx.x * 16;

    for (int i = tid; i < 16 * 260; i += 512) {
        ((float*)hL)[i] = 0.f; ((float*)cL)[i] = 0.f; ((float*)xL)[i] = 0.f;
    }
    for (int i = tid; i < 1024; i += 512)
        bcombL[i] = bs2f(wp.bih[i]) + bs2f(wp.bhh[i]);
    if (tid < 16) aL[tid] = 0.f;
    float bVd  = bs2f(wp.bvds[0]);
    __syncthreads();

    for (int t = 0; t < 96; ++t) {
        // stage x tile
        for (int i = tid; i < 16 * 256; i += 512) {
            int rr = i >> 8, chn = i & 255;
            xL[rr][chn] = bs2f(inputs[((row0 + rr) * 96 + t) * 256 + chn]);
        }
        __syncthreads();

        // ---- attention matvec: n = j*8 + nn
        float p = 0.f;
        long wrow = ((row0 + r) * 96 + t) * 256;
#pragma unroll
        for (int nn = 0; nn < 8; ++nn) {
            int n = j * 8 + nn;
            const ushort_t* wr = wp.wes + (long)n * 512;
            float s = 0.f;
            for (int k = 0; k < 256; ++k) s += hL[r][k] * bs2f(wr[k]);
            for (int k = 0; k < 256; ++k) s += cL[r][k] * bs2f(wr[256 + k]);
            s += bs2f(wi[wrow + n]);
            p += ftanh(s) * bs2f(wp.vds[n]);
        }
        // half-wave reduce (32 lanes of same r are contiguous in the wave)
#pragma unroll
        for (int m = 1; m < 32; m <<= 1) p += __shfl_xor(p, m, 64);
        if (j == 0) aL[r] = p + bVd;
        __syncthreads();

        // ---- gate matvec + cell: u = j*8 + uu
        float av = aL[r];
        float nh[8], nc[8];
#pragma unroll
        for (int uu = 0; uu < 8; ++uu) {
            int u = j * 8 + uu;
            float g[4];
#pragma unroll
            for (int gi = 0; gi < 4; ++gi) {
                int n = gi * 256 + u;
                const ushort_t* whr = wp.whh + (long)n * 256;
                const ushort_t* wir = wp.wih + (long)n * 256;
                float ah = 0.f, ax = 0.f;
                for (int k = 0; k < 256; ++k) {
                    ah += hL[r][k] * bs2f(whr[k]);
                    ax += xL[r][k] * bs2f(wir[k]);
                }
                g[gi] = ah + av * ax + bcombL[n];
            }
            float c2 = sigm(g[1]) * cL[r][u] + sigm(g[0]) * ftanh(g[2]);
            float h2 = sigm(g[3]) * ftanh(c2);
            nh[uu] = h2; nc[uu] = c2;
            mid[((row0 + r) * 96 + t) * 256 + u] = f2bs(h2);
        }
        __syncthreads();   // all hL/cL/xL reads of this step done
#pragma unroll
        for (int uu = 0; uu < 8; ++uu) {
            int u = j * 8 + uu;
            hL[r][u] = nh[uu]; cL[r][u] = nc[uu];
        }
        __syncthreads();   // state stable for next step
    }
}

// ---------------------------------------------------------------------------
// k_decoder: 1024 blocks (one batch row), 256 thr, 16 sequential steps.
// ---------------------------------------------------------------------------
__global__ __launch_bounds__(256) void k_decoder(
    const ushort_t* __restrict__ mid, const ushort_t* __restrict__ wd,
    WsPtrs wp, const int* __restrict__ flagp, void* __restrict__ out)
{
    __shared__ ushort_t wdl[96][264];
    __shared__ float qL[256], aLs[96], ctxL[256], VdtL[256], gL[4];
    __shared__ float st[3];

    int tid = threadIdx.x;
    long b = blockIdx.x;
    int bf = *flagp;

    for (int c = tid; c < 96 * 256; c += 256) {
        int tp = c >> 8, chn = c & 255;
        wdl[tp][chn] = wd[(b * 96 + tp) * 256 + chn];
    }
    qL[tid] = 0.f; ctxL[tid] = 0.f;
    if (tid < 96) aLs[tid] = 0.f;
    if (tid < 4)  gL[tid] = 0.f;
    VdtL[tid] = bs2f(wp.vdt[tid]);
    if (tid == 0) {
        st[0] = 0.f; st[1] = 0.f;
        st[2] = bs2f(mid[(b * 96 + 95) * 256 + 2]);
    }
    float bVdt = bs2f(wp.bvdt[0]);
    float w2a = bs2f(wp.wd2t[tid * 2]), w2b = bs2f(wp.wd2t[tid * 2 + 1]);
    __syncthreads();

    for (int s = 0; s < 16; ++s) {
        float hi = st[0], ci = st[1], prev = st[2];
        qL[tid] = hi * w2a + ci * w2b;
        __syncthreads();
        if (tid < 96) {
            float acc = 0.f;
            for (int u = 0; u < 256; ++u)
                acc += ftanh(qL[u] + bs2f(wdl[tid][u])) * VdtL[u];
            aLs[tid] = acc + bVdt;
        }
        __syncthreads();
        {
            float acc = 0.f;
            for (int tp = 0; tp < 96; ++tp)
                acc += aLs[tp] * bs2f(mid[(b * 96 + tp) * 256 + tid]);
            ctxL[tid] = acc;
        }
        __syncthreads();
        if (tid < 4) {
            float gv = bs2f(wp.bihd[tid]) + bs2f(wp.bhhd[tid])
                     + bs2f(wp.whhd[tid]) * hi
                     + bs2f(wp.wihd[tid * 257 + 256]) * prev;
            for (int u = 0; u < 256; ++u)
                gv += bs2f(wp.wihd[tid * 257 + u]) * ctxL[u];
            gL[tid] = gv;
        }
        __syncthreads();
        if (tid == 0) {
            float c2 = sigm(gL[1]) * ci + sigm(gL[0]) * ftanh(gL[2]);
            float h2 = sigm(gL[3]) * ftanh(c2);
            st[0] = h2; st[1] = c2; st[2] = h2;
            long oi = b * 16 + s;
            if (bf) ((ushort_t*)out)[oi] = f2bs(h2);
            else    ((float*)out)[oi] = h2;
        }
        __syncthreads();
    }
}

// ---------------------------------------------------------------------------
extern "C" void kernel_launch(void* const* d_in, const int* in_sizes, int n_in,
                              void* d_out, int out_size, void* d_ws, size_t ws_size,
                              hipStream_t stream)
{
    const long MT = 1024L * 96;   // 98304 rows

    // ws layout: [0,256) header(flag) | params bf16 (~1.55MB) | inputs | wi | mid
    int* flagp = (int*)d_ws;
    ushort_t* base = (ushort_t*)((char*)d_ws + 256);

    SrcPtrs sp;
    for (int i = 0; i < 26; ++i) sp.p[i] = d_in[i];

    static const long sizes[23] = {
        320, 10, 120, 24, 15, 65536, 256, 131072, 256, 1,
        262144, 262144, 1024, 1024, 65536, 256, 512, 256, 1,
        1028, 4, 4, 4
    };
    ushort_t* ptrs[23];
    long off = 0;
    for (int i = 0; i < 23; ++i) { ptrs[i] = base + off; off += sizes[i]; }
    off = (off + 7) & ~7L;        // align to 16B

    WsPtrs wp;
    wp.wcfg = ptrs[0];  wp.bcfg = ptrs[1];  wp.eh   = ptrs[2];  wp.ew   = ptrs[3];
    wp.es   = ptrs[4];  wp.wis  = ptrs[5];  wp.bis  = ptrs[6];  wp.wes  = ptrs[7];
    wp.vds  = ptrs[8];  wp.bvds = ptrs[9];  wp.whh  = ptrs[10]; wp.wih  = ptrs[11];
    wp.bih  = ptrs[12]; wp.bhh  = ptrs[13]; wp.wdt  = ptrs[14]; wp.bdt  = ptrs[15];
    wp.wd2t = ptrs[16]; wp.vdt  = ptrs[17]; wp.bvdt = ptrs[18]; wp.wihd = ptrs[19];
    wp.whhd = ptrs[20]; wp.bihd = ptrs[21]; wp.bhhd = ptrs[22];

    ushort_t* inputs = base + off;            // MT*256
    ushort_t* wib    = inputs + MT * 256;     // MT*256
    ushort_t* midb   = wib + MT * 256;        // MT*256
    ushort_t* wdb    = wib;                   // alias: wi dead after encoder

    k_detect<<<1, 64, 0, stream>>>(d_in[3], flagp);
    k_cvt<<<23, 256, 0, stream>>>(sp, wp, flagp);
    k_build<<<6144, 256, 0, stream>>>(d_in[0], d_in[1], (const int*)d_in[2],
                                      wp, flagp, inputs);
    k_rowmm<<<6144, 256, 0, stream>>>(inputs, wp.wis, wp.bis, wib);
    k_encoder<<<64, 512, 0, stream>>>(wib, inputs, wp, midb);
    k_rowmm<<<6144, 256, 0, stream>>>(midb, wp.wdt, wp.bdt, wdb);
    k_decoder<<<1024, 256, 0, stream>>>(midb, wdb, wp, flagp, d_out);
}

// Round 5
// 7147.752 us; speedup vs baseline: 12.6660x; 12.6660x over previous
//
#include <hip/hip_runtime.h>
#include <hip/hip_bf16.h>

// ---------------------------------------------------------------------------
// Round 5: R4's dtype-adaptive boundary (proven) + MFMA compute core.
//   k_detect : fp32-vs-bf16 by bit-pattern statistics of W_cfg
//   k_cvt    : canonicalize all 23 parameter tensors -> bf16 ws copies
//              (offsets padded to 8 elements => 16B-aligned vector loads)
//   k_build  : features (98304 x 256) -> ws bf16
//   k_gemm   : MFMA 128x128-tile GEMM: wi = inputs@Wi_s.T+b ; wd = mid@Wd_t.T+b
//   k_encoder: MFMA recurrence, 64 blocks x 512 thr, 16 batch rows/block,
//              gates = h@Whh.T + a*(x@Wih.T) + (bih+bhh); c-state fp32 in regs
//   k_decoder: scalar-hidden LSTM, 1024 blocks x 16 steps (R4's, proven)
// ---------------------------------------------------------------------------

typedef unsigned short ushort_t;
using short8  = __attribute__((ext_vector_type(8))) short;   // 8 x bf16
using floatx4 = __attribute__((ext_vector_type(4))) float;   // MFMA accumulator

#define DEVFN static __device__ __forceinline__

DEVFN float bs2f(ushort_t u) {
    union { float f; unsigned v; } c; c.v = ((unsigned)u) << 16; return c.f;
}
DEVFN ushort_t f2bs(float f) {
    __hip_bfloat16 h = __float2bfloat16(f);
    return *reinterpret_cast<ushort_t*>(&h);
}
DEVFN float gload(const void* p, long i, int bf) {
    if (bf) return bs2f(((const ushort_t*)p)[i]);
    return ((const float*)p)[i];
}
DEVFN float sigm(float x) { return 1.f / (1.f + __expf(-x)); }
DEVFN float ftanh(float x) {
    float t = __expf(-2.f * fabsf(x));
    float r = (1.f - t) / (1.f + t);
    return copysignf(r, x);
}
DEVFN short8 ld8(const ushort_t* p) { return *reinterpret_cast<const short8*>(p); }

struct SrcPtrs { const void* p[26]; };
struct WsPtrs {
    ushort_t *wcfg, *bcfg, *eh, *ew, *es, *wis, *bis, *wes, *vds, *bvds,
             *whh, *wih, *bih, *bhh, *wdt, *bdt, *wd2t, *vdt, *bvdt,
             *wihd, *whhd, *bihd, *bhhd;
};

// ---------------------------------------------------------------------------
__global__ void k_detect(const void* probe, int* flag) {
    if (threadIdx.x == 0 && blockIdx.x == 0) {
        const ushort_t* u = (const ushort_t*)probe;
        int ok = 1;
        for (int i = 0; i < 16; ++i) {
            ushort_t v = u[2 * i];
            int e = (v >> 7) & 0xFF;
            if (!(v == 0 || (e >= 96 && e <= 126))) ok = 0;
        }
        *flag = ok;
    }
}

// ---------------------------------------------------------------------------
__global__ __launch_bounds__(256) void k_cvt(SrcPtrs sp, WsPtrs wp, const int* flagp) {
    int bf = *flagp;
    const void* src = nullptr; ushort_t* dst = nullptr; long n = 0;
    switch (blockIdx.x) {
        case 0:  src = sp.p[3];  dst = wp.wcfg; n = 320;    break;
        case 1:  src = sp.p[4];  dst = wp.bcfg; n = 10;     break;
        case 2:  src = sp.p[5];  dst = wp.eh;   n = 120;    break;
        case 3:  src = sp.p[6];  dst = wp.ew;   n = 24;     break;
        case 4:  src = sp.p[7];  dst = wp.es;   n = 15;     break;
        case 5:  src = sp.p[16]; dst = wp.wis;  n = 65536;  break;
        case 6:  src = sp.p[17]; dst = wp.bis;  n = 256;    break;
        case 7:  src = sp.p[18]; dst = wp.wes;  n = 131072; break;
        case 8:  src = sp.p[19]; dst = wp.vds;  n = 256;    break;
        case 9:  src = sp.p[20]; dst = wp.bvds; n = 1;      break;
        case 10: src = sp.p[9];  dst = wp.whh;  n = 262144; break;
        case 11: src = sp.p[8];  dst = wp.wih;  n = 262144; break;
        case 12: src = sp.p[10]; dst = wp.bih;  n = 1024;   break;
        case 13: src = sp.p[11]; dst = wp.bhh;  n = 1024;   break;
        case 14: src = sp.p[21]; dst = wp.wdt;  n = 65536;  break;
        case 15: src = sp.p[22]; dst = wp.bdt;  n = 256;    break;
        case 16: src = sp.p[23]; dst = wp.wd2t; n = 512;    break;
        case 17: src = sp.p[24]; dst = wp.vdt;  n = 256;    break;
        case 18: src = sp.p[25]; dst = wp.bvdt; n = 1;      break;
        case 19: src = sp.p[12]; dst = wp.wihd; n = 1028;   break;
        case 20: src = sp.p[13]; dst = wp.whhd; n = 4;      break;
        case 21: src = sp.p[14]; dst = wp.bihd; n = 4;      break;
        case 22: src = sp.p[15]; dst = wp.bhhd; n = 4;      break;
        default: return;
    }
    for (long i = threadIdx.x; i < n; i += 256) {
        float v = bf ? bs2f(((const ushort_t*)src)[i]) : ((const float*)src)[i];
        dst[i] = f2bs(v);
    }
}

// ---------------------------------------------------------------------------
// k_build: features. 6144 blocks x 256 thr, 16 rows/block.
// ---------------------------------------------------------------------------
__global__ __launch_bounds__(256) void k_build(
    const void* __restrict__ pq, const void* __restrict__ cfg_in,
    const int* __restrict__ timei, WsPtrs wp, const int* __restrict__ flagp,
    ushort_t* __restrict__ inputs)
{
    int bf = *flagp;
    int ch = threadIdx.x;
    for (int rr = 0; rr < 16; ++rr) {
        long row = (long)blockIdx.x * 16 + rr;
        float v;
        if (ch < 235) {
            v = gload(pq, row * 235 + ch, bf);
        } else if (ch < 245) {
            int j = ch - 235;
            float acc = bs2f(wp.bcfg[j]);
            for (int k = 0; k < 32; ++k)
                acc += gload(cfg_in, row * 32 + k, bf) * bs2f(wp.wcfg[j * 32 + k]);
            v = acc;
        } else if (ch < 250) {
            v = bs2f(wp.eh[timei[row * 3 + 0] * 5 + (ch - 245)]);
        } else if (ch < 253) {
            v = bs2f(wp.ew[timei[row * 3 + 1] * 3 + (ch - 250)]);
        } else {
            v = bs2f(wp.es[timei[row * 3 + 2] * 3 + (ch - 253)]);
        }
        inputs[row * 256 + ch] = f2bs(v);
    }
}

// ---------------------------------------------------------------------------
// k_gemm: out = A @ W.T + bias. A:(98304x256) ws bf16, W:(256x256) ws bf16.
// 128x128 tiles, BK=32, 4 waves of 64x64. grid (768, 2).
// ---------------------------------------------------------------------------
__global__ __launch_bounds__(256) void k_gemm(
    const ushort_t* __restrict__ A, const ushort_t* __restrict__ W,
    const ushort_t* __restrict__ bias, ushort_t* __restrict__ out)
{
    const int K = 256;
    __shared__ alignas(16) ushort_t At[128][40];
    __shared__ alignas(16) ushort_t Bt[128][40];

    int tid  = threadIdx.x;
    int lane = tid & 63, wave = tid >> 6;
    int wm = wave >> 1, wn = wave & 1;
    int q = lane >> 4, ln = lane & 15;
    long mbase = (long)blockIdx.x * 128;
    const ushort_t* Wsrc = W + (long)blockIdx.y * 128 * K;

    floatx4 acc[4][4];
#pragma unroll
    for (int i = 0; i < 4; ++i)
#pragma unroll
        for (int j = 0; j < 4; ++j) acc[i][j] = (floatx4){0.f, 0.f, 0.f, 0.f};

    for (int k0 = 0; k0 < K; k0 += 32) {
        __syncthreads();
#pragma unroll
        for (int it = 0; it < 2; ++it) {
            int c = tid + it * 256;
            int r = c >> 2, kc = (c & 3) * 8;
            *reinterpret_cast<short8*>(&At[r][kc]) = ld8(&A[(mbase + r) * K + k0 + kc]);
            *reinterpret_cast<short8*>(&Bt[r][kc]) = ld8(&Wsrc[(long)r * K + k0 + kc]);
        }
        __syncthreads();
        short8 af[4];
#pragma unroll
        for (int mt = 0; mt < 4; ++mt)
            af[mt] = *reinterpret_cast<const short8*>(&At[wm * 64 + mt * 16 + ln][q * 8]);
#pragma unroll
        for (int nt = 0; nt < 4; ++nt) {
            short8 bf = *reinterpret_cast<const short8*>(&Bt[wn * 64 + nt * 16 + ln][q * 8]);
#pragma unroll
            for (int mt = 0; mt < 4; ++mt)
                acc[mt][nt] = __builtin_amdgcn_mfma_f32_16x16x32_bf16(af[mt], bf, acc[mt][nt], 0, 0, 0);
        }
    }

#pragma unroll
    for (int mt = 0; mt < 4; ++mt)
#pragma unroll
        for (int nt = 0; nt < 4; ++nt)
#pragma unroll
            for (int reg = 0; reg < 4; ++reg) {
                long row = mbase + wm * 64 + mt * 16 + q * 4 + reg;
                int  col = blockIdx.y * 128 + wn * 64 + nt * 16 + ln;
                out[row * 256 + col] = f2bs(acc[mt][nt][reg] + bs2f(bias[col]));
            }
}

// ---------------------------------------------------------------------------
// k_encoder: 64 blocks x 512 threads (8 waves), 16 batch rows/block, 96 steps.
// Wave w owns u-slice [w*32, w*32+32). Per step t:
//   stage x tile; matvec1 attn -> aPart; barrier A; a[r]=sum+bVd;
//   matvec2 accH=h@Whh.T, accX=x@Wih.T (gate-interleaved); barrier B;
//   gates=accH+a*accX+bcomb -> cell (fp32 c in regs) -> write hc; barrier C.
// ---------------------------------------------------------------------------
__global__ __launch_bounds__(512) void k_encoder(
    const ushort_t* __restrict__ wi, const ushort_t* __restrict__ inputs,
    WsPtrs wp, ushort_t* __restrict__ mid)
{
    __shared__ alignas(16) ushort_t hc[16][520];   // [h(0:256)|c(256:512)]
    __shared__ alignas(16) ushort_t xs[16][264];   // x tile
    __shared__ float bcomb[1024];
    __shared__ float VdsL[256];
    __shared__ float aPart[16][8];

    int tid  = threadIdx.x;
    int lane = tid & 63, w = tid >> 6;
    int q = lane >> 4, ln = lane & 15;
    long row0 = (long)blockIdx.x * 16;

    const ushort_t* Wes = wp.wes;
    const ushort_t* Whh = wp.whh;
    const ushort_t* Wih = wp.wih;

    for (int i = tid; i < 16 * 520; i += 512) ((ushort_t*)hc)[i] = 0;
    for (int i = tid; i < 16 * 264; i += 512) ((ushort_t*)xs)[i] = 0;
    for (int i = tid; i < 1024; i += 512) bcomb[i] = bs2f(wp.bih[i]) + bs2f(wp.bhh[i]);
    for (int i = tid; i < 256; i += 512) VdsL[i] = bs2f(wp.vds[i]);
    for (int i = tid; i < 16 * 8; i += 512) ((float*)aPart)[i] = 0.f;
    float bVd = bs2f(wp.bvds[0]);
    float creg[8];
#pragma unroll
    for (int i = 0; i < 8; ++i) creg[i] = 0.f;
    __syncthreads();

    for (int t = 0; t < 96; ++t) {
        // ---- stage x tile for step t
        {
            int r = tid >> 5, kb = (tid & 31) * 8;
            *reinterpret_cast<short8*>(&xs[r][kb]) =
                ld8(&inputs[((row0 + r) * 96 + t) * 256 + kb]);
        }

        // ---- matvec1: [h|c](16x512) @ Wes.T cols [w*32, w*32+32)
        floatx4 acc1a = (floatx4){0.f, 0.f, 0.f, 0.f};
        floatx4 acc1b = (floatx4){0.f, 0.f, 0.f, 0.f};
#pragma unroll
        for (int kk = 0; kk < 16; ++kk) {
            int k0 = kk * 32 + q * 8;
            short8 af = *reinterpret_cast<const short8*>(&hc[ln][k0]);
            short8 b0 = ld8(&Wes[(w * 32 + ln) * 512 + k0]);
            short8 b1 = ld8(&Wes[(w * 32 + 16 + ln) * 512 + k0]);
            acc1a = __builtin_amdgcn_mfma_f32_16x16x32_bf16(af, b0, acc1a, 0, 0, 0);
            acc1b = __builtin_amdgcn_mfma_f32_16x16x32_bf16(af, b1, acc1b, 0, 0, 0);
        }
        float p[4];
#pragma unroll
        for (int reg = 0; reg < 4; ++reg) {
            int r = q * 4 + reg;
            long wrow = ((row0 + r) * 96 + t) * 256;
            float s0 = acc1a[reg] + bs2f(wi[wrow + (w * 32 + ln)]);
            float s1 = acc1b[reg] + bs2f(wi[wrow + (w * 32 + 16 + ln)]);
            p[reg] = ftanh(s0) * VdsL[w * 32 + ln] + ftanh(s1) * VdsL[w * 32 + 16 + ln];
        }
#pragma unroll
        for (int m = 1; m < 16; m <<= 1) {
#pragma unroll
            for (int reg = 0; reg < 4; ++reg) p[reg] += __shfl_xor(p[reg], m, 64);
        }
        if (ln == 0) {
#pragma unroll
            for (int reg = 0; reg < 4; ++reg) aPart[q * 4 + reg][w] = p[reg];
        }
        __syncthreads();   // barrier A

        float aval[4];
#pragma unroll
        for (int reg = 0; reg < 4; ++reg) {
            float s = bVd;
#pragma unroll
            for (int ww = 0; ww < 8; ++ww) s += aPart[q * 4 + reg][ww];
            aval[reg] = s;
        }

        // ---- matvec2: accH = h@Whh.T, accX = x@Wih.T
        floatx4 aH[4][2], aX[4][2];
#pragma unroll
        for (int g = 0; g < 4; ++g)
#pragma unroll
            for (int pp = 0; pp < 2; ++pp) {
                aH[g][pp] = (floatx4){0.f, 0.f, 0.f, 0.f};
                aX[g][pp] = (floatx4){0.f, 0.f, 0.f, 0.f};
            }
#pragma unroll
        for (int kk = 0; kk < 8; ++kk) {
            int k0 = kk * 32 + q * 8;
            short8 afh = *reinterpret_cast<const short8*>(&hc[ln][k0]);
            short8 afx = *reinterpret_cast<const short8*>(&xs[ln][k0]);
#pragma unroll
            for (int g = 0; g < 4; ++g)
#pragma unroll
                for (int pp = 0; pp < 2; ++pp) {
                    long wr = (long)(g * 256 + w * 32 + pp * 16 + ln) * 256 + k0;
                    aH[g][pp] = __builtin_amdgcn_mfma_f32_16x16x32_bf16(afh, ld8(&Whh[wr]), aH[g][pp], 0, 0, 0);
                    aX[g][pp] = __builtin_amdgcn_mfma_f32_16x16x32_bf16(afx, ld8(&Wih[wr]), aX[g][pp], 0, 0, 0);
                }
        }
        __syncthreads();   // barrier B

        // ---- cell update: rows q*4+reg, cols w*32+pp*16+ln
#pragma unroll
        for (int pp = 0; pp < 2; ++pp) {
            int u = w * 32 + pp * 16 + ln;
#pragma unroll
            for (int reg = 0; reg < 4; ++reg) {
                float gi = aH[0][pp][reg] + aval[reg] * aX[0][pp][reg] + bcomb[u];
                float gf = aH[1][pp][reg] + aval[reg] * aX[1][pp][reg] + bcomb[256 + u];
                float gg = aH[2][pp][reg] + aval[reg] * aX[2][pp][reg] + bcomb[512 + u];
                float go = aH[3][pp][reg] + aval[reg] * aX[3][pp][reg] + bcomb[768 + u];
                float c2 = sigm(gf) * creg[reg * 2 + pp] + sigm(gi) * ftanh(gg);
                float h2 = sigm(go) * ftanh(c2);
                creg[reg * 2 + pp] = c2;
                int r = q * 4 + reg;
                hc[r][u] = f2bs(h2);
                hc[r][256 + u] = f2bs(c2);
                mid[((row0 + r) * 96 + t) * 256 + u] = f2bs(h2);
            }
        }
        __syncthreads();   // barrier C
    }
}

// ---------------------------------------------------------------------------
// k_decoder: 1024 blocks (one batch row), 256 thr, 16 sequential steps.
// ---------------------------------------------------------------------------
__global__ __launch_bounds__(256) void k_decoder(
    const ushort_t* __restrict__ mid, const ushort_t* __restrict__ wd,
    WsPtrs wp, const int* __restrict__ flagp, void* __restrict__ out)
{
    __shared__ ushort_t wdl[96][264];
    __shared__ float qL[256], aLs[96], ctxL[256], VdtL[256], gL[4];
    __shared__ float st[3];

    int tid = threadIdx.x;
    long b = blockIdx.x;
    int bf = *flagp;

    for (int c = tid; c < 96 * 256; c += 256) {
        int tp = c >> 8, chn = c & 255;
        wdl[tp][chn] = wd[(b * 96 + tp) * 256 + chn];
    }
    qL[tid] = 0.f; ctxL[tid] = 0.f;
    if (tid < 96) aLs[tid] = 0.f;
    if (tid < 4)  gL[tid] = 0.f;
    VdtL[tid] = bs2f(wp.vdt[tid]);
    if (tid == 0) {
        st[0] = 0.f; st[1] = 0.f;
        st[2] = bs2f(mid[(b * 96 + 95) * 256 + 2]);
    }
    float bVdt = bs2f(wp.bvdt[0]);
    float w2a = bs2f(wp.wd2t[tid * 2]), w2b = bs2f(wp.wd2t[tid * 2 + 1]);
    __syncthreads();

    for (int s = 0; s < 16; ++s) {
        float hi = st[0], ci = st[1], prev = st[2];
        qL[tid] = hi * w2a + ci * w2b;
        __syncthreads();
        if (tid < 96) {
            float acc = 0.f;
            for (int u = 0; u < 256; ++u)
                acc += ftanh(qL[u] + bs2f(wdl[tid][u])) * VdtL[u];
            aLs[tid] = acc + bVdt;
        }
        __syncthreads();
        {
            float acc = 0.f;
            for (int tp = 0; tp < 96; ++tp)
                acc += aLs[tp] * bs2f(mid[(b * 96 + tp) * 256 + tid]);
            ctxL[tid] = acc;
        }
        __syncthreads();
        if (tid < 4) {
            float gv = bs2f(wp.bihd[tid]) + bs2f(wp.bhhd[tid])
                     + bs2f(wp.whhd[tid]) * hi
                     + bs2f(wp.wihd[tid * 257 + 256]) * prev;
            for (int u = 0; u < 256; ++u)
                gv += bs2f(wp.wihd[tid * 257 + u]) * ctxL[u];
            gL[tid] = gv;
        }
        __syncthreads();
        if (tid == 0) {
            float c2 = sigm(gL[1]) * ci + sigm(gL[0]) * ftanh(gL[2]);
            float h2 = sigm(gL[3]) * ftanh(c2);
            st[0] = h2; st[1] = c2; st[2] = h2;
            long oi = b * 16 + s;
            if (bf) ((ushort_t*)out)[oi] = f2bs(h2);
            else    ((float*)out)[oi] = h2;
        }
        __syncthreads();
    }
}

// ---------------------------------------------------------------------------
extern "C" void kernel_launch(void* const* d_in, const int* in_sizes, int n_in,
                              void* d_out, int out_size, void* d_ws, size_t ws_size,
                              hipStream_t stream)
{
    const long MT = 1024L * 96;   // 98304 rows

    int* flagp = (int*)d_ws;
    ushort_t* base = (ushort_t*)((char*)d_ws + 256);

    SrcPtrs sp;
    for (int i = 0; i < 26; ++i) sp.p[i] = d_in[i];

    static const long sizes[23] = {
        320, 10, 120, 24, 15, 65536, 256, 131072, 256, 1,
        262144, 262144, 1024, 1024, 65536, 256, 512, 256, 1,
        1028, 4, 4, 4
    };
    ushort_t* ptrs[23];
    long off = 0;
    for (int i = 0; i < 23; ++i) {
        ptrs[i] = base + off;
        off += (sizes[i] + 7) & ~7L;   // 8-element (16B) aligned layout
    }

    WsPtrs wp;
    wp.wcfg = ptrs[0];  wp.bcfg = ptrs[1];  wp.eh   = ptrs[2];  wp.ew   = ptrs[3];
    wp.es   = ptrs[4];  wp.wis  = ptrs[5];  wp.bis  = ptrs[6];  wp.wes  = ptrs[7];
    wp.vds  = ptrs[8];  wp.bvds = ptrs[9];  wp.whh  = ptrs[10]; wp.wih  = ptrs[11];
    wp.bih  = ptrs[12]; wp.bhh  = ptrs[13]; wp.wdt  = ptrs[14]; wp.bdt  = ptrs[15];
    wp.wd2t = ptrs[16]; wp.vdt  = ptrs[17]; wp.bvdt = ptrs[18]; wp.wihd = ptrs[19];
    wp.whhd = ptrs[20]; wp.bihd = ptrs[21]; wp.bhhd = ptrs[22];

    ushort_t* inputs = base + off;            // MT*256
    ushort_t* wib    = inputs + MT * 256;     // MT*256
    ushort_t* midb   = wib + MT * 256;        // MT*256
    ushort_t* wdb    = wib;                   // alias: wi dead after encoder

    k_detect<<<1, 64, 0, stream>>>(d_in[3], flagp);
    k_cvt<<<23, 256, 0, stream>>>(sp, wp, flagp);
    k_build<<<6144, 256, 0, stream>>>(d_in[0], d_in[1], (const int*)d_in[2],
                                      wp, flagp, inputs);
    k_gemm<<<dim3(768, 2), 256, 0, stream>>>(inputs, wp.wis, wp.bis, wib);
    k_encoder<<<64, 512, 0, stream>>>(wib, inputs, wp, midb);
    k_gemm<<<dim3(768, 2), 256, 0, stream>>>(midb, wp.wdt, wp.bdt, wdb);
    k_decoder<<<1024, 256, 0, stream>>>(midb, wdb, wp, flagp, d_out);
}

// Round 6
// 3143.450 us; speedup vs baseline: 28.8006x; 2.2739x over previous
//
#include <hip/hip_runtime.h>
#include <hip/hip_bf16.h>

// ---------------------------------------------------------------------------
// Round 6: coalesced fragment-major weights for the encoder.
//   k_detect : fp32-vs-bf16 by bit-pattern statistics of W_cfg
//   k_cvt    : small parameter tensors -> bf16 ws copies
//   k_permA/B: Whh,Wih,Wes -> MFMA-fragment-major bf16 layout
//              (chunk=(wave,ktile[,gate]), intra-chunk = lane*8 els =>
//               every encoder weight load is one 1KB coalesced transaction)
//   k_build  : features (98304 x 256) -> ws bf16 (4 rows/block)
//   k_gemm   : MFMA 128x128 GEMM: wi = inputs@Wi_s.T+b ; wd = mid@Wd_t.T+b
//   k_encoder: 64 blocks x 1024 thr (16 waves, 4/SIMD), 16 batch rows/block;
//              wave owns 16 cols; gates = h@Whh.T + a*(x@Wih.T) + b
//   k_decoder: 1024 blocks x 16 steps; attn + gate matvecs lane-parallel
// ---------------------------------------------------------------------------

typedef unsigned short ushort_t;
using short8  = __attribute__((ext_vector_type(8))) short;   // 8 x bf16
using floatx4 = __attribute__((ext_vector_type(4))) float;   // MFMA accumulator

#define DEVFN static __device__ __forceinline__

DEVFN float bs2f(ushort_t u) {
    union { float f; unsigned v; } c; c.v = ((unsigned)u) << 16; return c.f;
}
DEVFN ushort_t f2bs(float f) {
    __hip_bfloat16 h = __float2bfloat16(f);
    return *reinterpret_cast<ushort_t*>(&h);
}
DEVFN float gload(const void* p, long i, int bf) {
    if (bf) return bs2f(((const ushort_t*)p)[i]);
    return ((const float*)p)[i];
}
DEVFN float sigm(float x) { return 1.f / (1.f + __expf(-x)); }
DEVFN float ftanh(float x) {
    float t = __expf(-2.f * fabsf(x));
    float r = (1.f - t) / (1.f + t);
    return copysignf(r, x);
}
DEVFN short8 ld8(const ushort_t* p) { return *reinterpret_cast<const short8*>(p); }

struct SrcPtrs { const void* p[26]; };
struct WsPtrs {
    // wes/whh/wih hold PERMUTED (fragment-major) data, written by k_perm*.
    ushort_t *wcfg, *bcfg, *eh, *ew, *es, *wis, *bis, *wes, *vds, *bvds,
             *whh, *wih, *bih, *bhh, *wdt, *bdt, *wd2t, *vdt, *bvdt,
             *wihd, *whhd, *bihd, *bhhd;
};

// ---------------------------------------------------------------------------
__global__ void k_detect(const void* probe, int* flag) {
    if (threadIdx.x == 0 && blockIdx.x == 0) {
        const ushort_t* u = (const ushort_t*)probe;
        int ok = 1;
        for (int i = 0; i < 16; ++i) {
            ushort_t v = u[2 * i];
            int e = (v >> 7) & 0xFF;
            if (!(v == 0 || (e >= 96 && e <= 126))) ok = 0;
        }
        *flag = ok;
    }
}

// ---------------------------------------------------------------------------
// k_cvt: small tensors only (wes/whh/wih are handled by the perm kernels).
// ---------------------------------------------------------------------------
__global__ __launch_bounds__(256) void k_cvt(SrcPtrs sp, WsPtrs wp, const int* flagp) {
    int bf = *flagp;
    const void* src = nullptr; ushort_t* dst = nullptr; long n = 0;
    switch (blockIdx.x) {
        case 0:  src = sp.p[3];  dst = wp.wcfg; n = 320;    break;
        case 1:  src = sp.p[4];  dst = wp.bcfg; n = 10;     break;
        case 2:  src = sp.p[5];  dst = wp.eh;   n = 120;    break;
        case 3:  src = sp.p[6];  dst = wp.ew;   n = 24;     break;
        case 4:  src = sp.p[7];  dst = wp.es;   n = 15;     break;
        case 5:  src = sp.p[16]; dst = wp.wis;  n = 65536;  break;
        case 6:  src = sp.p[17]; dst = wp.bis;  n = 256;    break;
        case 8:  src = sp.p[19]; dst = wp.vds;  n = 256;    break;
        case 9:  src = sp.p[20]; dst = wp.bvds; n = 1;      break;
        case 12: src = sp.p[10]; dst = wp.bih;  n = 1024;   break;
        case 13: src = sp.p[11]; dst = wp.bhh;  n = 1024;   break;
        case 14: src = sp.p[21]; dst = wp.wdt;  n = 65536;  break;
        case 15: src = sp.p[22]; dst = wp.bdt;  n = 256;    break;
        case 16: src = sp.p[23]; dst = wp.wd2t; n = 512;    break;
        case 17: src = sp.p[24]; dst = wp.vdt;  n = 256;    break;
        case 18: src = sp.p[25]; dst = wp.bvdt; n = 1;      break;
        case 19: src = sp.p[12]; dst = wp.wihd; n = 1028;   break;
        case 20: src = sp.p[13]; dst = wp.whhd; n = 4;      break;
        case 21: src = sp.p[14]; dst = wp.bihd; n = 4;      break;
        case 22: src = sp.p[15]; dst = wp.bhhd; n = 4;      break;
        default: return;
    }
    for (long i = threadIdx.x; i < n; i += 256) {
        float v = bf ? bs2f(((const ushort_t*)src)[i]) : ((const float*)src)[i];
        dst[i] = f2bs(v);
    }
}

// ---------------------------------------------------------------------------
// k_permA: Whh,Wih (1024x256 row-major) -> fragment-major.
// dst index p: chunk c=p>>9 (512 el = 64 lanes x 8), l=(p>>3)&63, e=p&7.
// c = w*32 + kk*4 + g  (w=wave 0..15, kk=ktile 0..7, g=gate 0..3).
// src row = g*256 + w*16 + (l&15); src col = kk*32 + (l>>4)*8 + e.
// grid (128, 2): y=0 -> Whh, y=1 -> Wih. 2048 els/block.
// ---------------------------------------------------------------------------
__global__ __launch_bounds__(256) void k_permA(
    const void* whh_src, const void* wih_src,
    ushort_t* whhp, ushort_t* wihp, const int* flagp)
{
    int bf = *flagp;
    const void* src = blockIdx.y ? wih_src : whh_src;
    ushort_t*   dst = blockIdx.y ? wihp    : whhp;
    long base = (long)blockIdx.x * 2048;
#pragma unroll
    for (int ii = 0; ii < 8; ++ii) {
        long p = base + threadIdx.x + ii * 256;
        int c = (int)(p >> 9), l = (int)((p >> 3) & 63), e = (int)(p & 7);
        int w = c >> 5, kk = (c >> 2) & 7, g = c & 3;
        int q = l >> 4, ln = l & 15;
        long si = (long)(g * 256 + w * 16 + ln) * 256 + kk * 32 + q * 8 + e;
        dst[p] = f2bs(gload(src, si, bf));
    }
}

// ---------------------------------------------------------------------------
// k_permB: Wes (256x512 row-major) -> fragment-major. c = w*16 + kk (kk 0..15).
// src row = w*16 + (l&15); src col = kk*32 + (l>>4)*8 + e. grid 64 blocks.
// ---------------------------------------------------------------------------
__global__ __launch_bounds__(256) void k_permB(
    const void* wes_src, ushort_t* wesp, const int* flagp)
{
    int bf = *flagp;
    long base = (long)blockIdx.x * 2048;
#pragma unroll
    for (int ii = 0; ii < 8; ++ii) {
        long p = base + threadIdx.x + ii * 256;
        int c = (int)(p >> 9), l = (int)((p >> 3) & 63), e = (int)(p & 7);
        int w = c >> 4, kk = c & 15;
        int q = l >> 4, ln = l & 15;
        long si = (long)(w * 16 + ln) * 512 + kk * 32 + q * 8 + e;
        wesp[p] = f2bs(gload(wes_src, si, bf));
    }
}

// ---------------------------------------------------------------------------
// k_build: features. 24576 blocks x 256 thr, 4 rows/block.
// ---------------------------------------------------------------------------
__global__ __launch_bounds__(256) void k_build(
    const void* __restrict__ pq, const void* __restrict__ cfg_in,
    const int* __restrict__ timei, WsPtrs wp, const int* __restrict__ flagp,
    ushort_t* __restrict__ inputs)
{
    int bf = *flagp;
    int ch = threadIdx.x;
    for (int rr = 0; rr < 4; ++rr) {
        long row = (long)blockIdx.x * 4 + rr;
        float v;
        if (ch < 235) {
            v = gload(pq, row * 235 + ch, bf);
        } else if (ch < 245) {
            int j = ch - 235;
            float acc = bs2f(wp.bcfg[j]);
            for (int k = 0; k < 32; ++k)
                acc += gload(cfg_in, row * 32 + k, bf) * bs2f(wp.wcfg[j * 32 + k]);
            v = acc;
        } else if (ch < 250) {
            v = bs2f(wp.eh[timei[row * 3 + 0] * 5 + (ch - 245)]);
        } else if (ch < 253) {
            v = bs2f(wp.ew[timei[row * 3 + 1] * 3 + (ch - 250)]);
        } else {
            v = bs2f(wp.es[timei[row * 3 + 2] * 3 + (ch - 253)]);
        }
        inputs[row * 256 + ch] = f2bs(v);
    }
}

// ---------------------------------------------------------------------------
// k_gemm: out = A @ W.T + bias. A:(98304x256), W:(256x256) row-major ws bf16.
// 128x128 tiles, BK=32, 4 waves of 64x64. grid (768, 2). (proven R5)
// ---------------------------------------------------------------------------
__global__ __launch_bounds__(256) void k_gemm(
    const ushort_t* __restrict__ A, const ushort_t* __restrict__ W,
    const ushort_t* __restrict__ bias, ushort_t* __restrict__ out)
{
    const int K = 256;
    __shared__ alignas(16) ushort_t At[128][40];
    __shared__ alignas(16) ushort_t Bt[128][40];

    int tid  = threadIdx.x;
    int lane = tid & 63, wave = tid >> 6;
    int wm = wave >> 1, wn = wave & 1;
    int q = lane >> 4, ln = lane & 15;
    long mbase = (long)blockIdx.x * 128;
    const ushort_t* Wsrc = W + (long)blockIdx.y * 128 * K;

    floatx4 acc[4][4];
#pragma unroll
    for (int i = 0; i < 4; ++i)
#pragma unroll
        for (int j = 0; j < 4; ++j) acc[i][j] = (floatx4){0.f, 0.f, 0.f, 0.f};

    for (int k0 = 0; k0 < K; k0 += 32) {
        __syncthreads();
#pragma unroll
        for (int it = 0; it < 2; ++it) {
            int c = tid + it * 256;
            int r = c >> 2, kc = (c & 3) * 8;
            *reinterpret_cast<short8*>(&At[r][kc]) = ld8(&A[(mbase + r) * K + k0 + kc]);
            *reinterpret_cast<short8*>(&Bt[r][kc]) = ld8(&Wsrc[(long)r * K + k0 + kc]);
        }
        __syncthreads();
        short8 af[4];
#pragma unroll
        for (int mt = 0; mt < 4; ++mt)
            af[mt] = *reinterpret_cast<const short8*>(&At[wm * 64 + mt * 16 + ln][q * 8]);
#pragma unroll
        for (int nt = 0; nt < 4; ++nt) {
            short8 bf = *reinterpret_cast<const short8*>(&Bt[wn * 64 + nt * 16 + ln][q * 8]);
#pragma unroll
            for (int mt = 0; mt < 4; ++mt)
                acc[mt][nt] = __builtin_amdgcn_mfma_f32_16x16x32_bf16(af[mt], bf, acc[mt][nt], 0, 0, 0);
        }
    }

#pragma unroll
    for (int mt = 0; mt < 4; ++mt)
#pragma unroll
        for (int nt = 0; nt < 4; ++nt)
#pragma unroll
            for (int reg = 0; reg < 4; ++reg) {
                long row = mbase + wm * 64 + mt * 16 + q * 4 + reg;
                int  col = blockIdx.y * 128 + wn * 64 + nt * 16 + ln;
                out[row * 256 + col] = f2bs(acc[mt][nt][reg] + bs2f(bias[col]));
            }
}

// ---------------------------------------------------------------------------
// k_encoder: 64 blocks x 1024 thr (16 waves, 4/SIMD), 16 batch rows/block.
// Wave w owns col-slice [w*16, w*16+16). All weight loads are 1KB coalesced
// (fragment-major layout). Per step: stage x; attn matvec -> aPart; barrier A;
// gates matvecs; barrier B; cell (fp32 c in regs) -> write hc; barrier C.
// ---------------------------------------------------------------------------
__global__ __launch_bounds__(1024, 4) void k_encoder(
    const ushort_t* __restrict__ wi, const ushort_t* __restrict__ inputs,
    WsPtrs wp, ushort_t* __restrict__ mid)
{
    __shared__ alignas(16) ushort_t hc[16][520];   // [h(0:256)|c(256:512)]
    __shared__ alignas(16) ushort_t xs[16][264];   // x tile
    __shared__ float bcomb[1024];
    __shared__ float VdsL[256];
    __shared__ float aPart[16][16];

    int tid  = threadIdx.x;
    int lane = tid & 63, w = tid >> 6;             // w in [0,16)
    int q = lane >> 4, ln = lane & 15;
    long row0 = (long)blockIdx.x * 16;

    const ushort_t* wesp = wp.wes;
    const ushort_t* whhp = wp.whh;
    const ushort_t* wihp = wp.wih;

    for (int i = tid; i < 16 * 520; i += 1024) ((ushort_t*)hc)[i] = 0;
    for (int i = tid; i < 16 * 264; i += 1024) ((ushort_t*)xs)[i] = 0;
    if (tid < 1024) bcomb[tid] = bs2f(wp.bih[tid]) + bs2f(wp.bhh[tid]);
    if (tid < 256) VdsL[tid] = bs2f(wp.vds[tid]);
    if (tid < 256) ((float*)aPart)[tid] = 0.f;
    float bVd = bs2f(wp.bvds[0]);
    float creg[4];
#pragma unroll
    for (int i = 0; i < 4; ++i) creg[i] = 0.f;
    __syncthreads();

    for (int t = 0; t < 96; ++t) {
        // ---- stage x tile for step t (xs last read before barrier C of t-1)
        if (tid < 512) {
            int r = tid >> 5, kb = (tid & 31) * 8;
            *reinterpret_cast<short8*>(&xs[r][kb]) =
                ld8(&inputs[((row0 + r) * 96 + t) * 256 + kb]);
        }

        // ---- attn matvec: cols [w*16, w*16+16), K=512 over [h|c]
        floatx4 acc1 = (floatx4){0.f, 0.f, 0.f, 0.f};
#pragma unroll 4
        for (int kk = 0; kk < 16; ++kk) {
            int k0 = kk * 32 + q * 8;
            short8 af = *reinterpret_cast<const short8*>(&hc[ln][k0]);
            short8 bf = ld8(&wesp[((long)(w * 16 + kk) << 9) + lane * 8]);
            acc1 = __builtin_amdgcn_mfma_f32_16x16x32_bf16(af, bf, acc1, 0, 0, 0);
        }
        float p4[4];
#pragma unroll
        for (int reg = 0; reg < 4; ++reg) {
            int r = q * 4 + reg;
            long wrow = ((row0 + r) * 96 + t) * 256;
            float s0 = acc1[reg] + bs2f(wi[wrow + w * 16 + ln]);
            p4[reg] = ftanh(s0) * VdsL[w * 16 + ln];
        }
#pragma unroll
        for (int m = 1; m < 16; m <<= 1) {
#pragma unroll
            for (int reg = 0; reg < 4; ++reg) p4[reg] += __shfl_xor(p4[reg], m, 64);
        }
        if (ln == 0) {
#pragma unroll
            for (int reg = 0; reg < 4; ++reg) aPart[q * 4 + reg][w] = p4[reg];
        }
        __syncthreads();   // barrier A: aPart + xs visible

        float aval[4];
#pragma unroll
        for (int reg = 0; reg < 4; ++reg) {
            float s = bVd;
#pragma unroll
            for (int ww = 0; ww < 16; ++ww) s += aPart[q * 4 + reg][ww];
            aval[reg] = s;
        }

        // ---- gate matvecs: aH = h@Whh.T, aX = x@Wih.T for u-slice w*16+ln
        floatx4 aH[4], aX[4];
#pragma unroll
        for (int g = 0; g < 4; ++g) {
            aH[g] = (floatx4){0.f, 0.f, 0.f, 0.f};
            aX[g] = (floatx4){0.f, 0.f, 0.f, 0.f};
        }
#pragma unroll 2
        for (int kk = 0; kk < 8; ++kk) {
            int k0 = kk * 32 + q * 8;
            short8 afh = *reinterpret_cast<const short8*>(&hc[ln][k0]);
            short8 afx = *reinterpret_cast<const short8*>(&xs[ln][k0]);
#pragma unroll
            for (int g = 0; g < 4; ++g) {
                long cb = ((long)((w * 8 + kk) * 4 + g) << 9) + lane * 8;
                aH[g] = __builtin_amdgcn_mfma_f32_16x16x32_bf16(afh, ld8(&whhp[cb]), aH[g], 0, 0, 0);
                aX[g] = __builtin_amdgcn_mfma_f32_16x16x32_bf16(afx, ld8(&wihp[cb]), aX[g], 0, 0, 0);
            }
        }
        __syncthreads();   // barrier B: all hc/xs reads of this step complete

        // ---- cell update: rows q*4+reg, col u = w*16+ln
        int u = w * 16 + ln;
#pragma unroll
        for (int reg = 0; reg < 4; ++reg) {
            float gi = aH[0][reg] + aval[reg] * aX[0][reg] + bcomb[u];
            float gf = aH[1][reg] + aval[reg] * aX[1][reg] + bcomb[256 + u];
            float gg = aH[2][reg] + aval[reg] * aX[2][reg] + bcomb[512 + u];
            float go = aH[3][reg] + aval[reg] * aX[3][reg] + bcomb[768 + u];
            float c2 = sigm(gf) * creg[reg] + sigm(gi) * ftanh(gg);
            float h2 = sigm(go) * ftanh(c2);
            creg[reg] = c2;
            int r = q * 4 + reg;
            hc[r][u] = f2bs(h2);
            hc[r][256 + u] = f2bs(c2);
            mid[((row0 + r) * 96 + t) * 256 + u] = f2bs(h2);
        }
        __syncthreads();   // barrier C: hc/xs stable for next step
    }
}

// ---------------------------------------------------------------------------
// k_decoder: 1024 blocks (one batch row), 256 thr, 16 sequential steps.
// attn: wave v handles t-points v,v+4,...; 64 lanes split the 256-dot.
// gates: wave g computes gate g; 64 lanes split the 256-dot.
// ---------------------------------------------------------------------------
__global__ __launch_bounds__(256) void k_decoder(
    const ushort_t* __restrict__ mid, const ushort_t* __restrict__ wd,
    WsPtrs wp, const int* __restrict__ flagp, void* __restrict__ out)
{
    __shared__ ushort_t wdl[96][264];
    __shared__ float qL[256], aLs[96], ctxL[256], VdtL[256], gL[4];
    __shared__ float st[3];

    int tid = threadIdx.x;
    long b = blockIdx.x;
    int bf = *flagp;

    for (int c = tid; c < 96 * 256; c += 256) {
        int tp = c >> 8, chn = c & 255;
        wdl[tp][chn] = wd[(b * 96 + tp) * 256 + chn];
    }
    qL[tid] = 0.f; ctxL[tid] = 0.f;
    if (tid < 96) aLs[tid] = 0.f;
    if (tid < 4)  gL[tid] = 0.f;
    VdtL[tid] = bs2f(wp.vdt[tid]);
    if (tid == 0) {
        st[0] = 0.f; st[1] = 0.f;
        st[2] = bs2f(mid[(b * 96 + 95) * 256 + 2]);
    }
    float bVdt = bs2f(wp.bvdt[0]);
    float w2a = bs2f(wp.wd2t[tid * 2]), w2b = bs2f(wp.wd2t[tid * 2 + 1]);
    __syncthreads();

    for (int s = 0; s < 16; ++s) {
        float hi = st[0], ci = st[1], prev = st[2];
        qL[tid] = hi * w2a + ci * w2b;
        __syncthreads();
        {   // attn scores: wave v, lanes split the 256-dot
            int v = tid >> 6, l = tid & 63;
            for (int tp = v; tp < 96; tp += 4) {
                float sacc = 0.f;
#pragma unroll
                for (int e = 0; e < 4; ++e) {
                    int u = l * 4 + e;
                    sacc += ftanh(qL[u] + bs2f(wdl[tp][u])) * VdtL[u];
                }
#pragma unroll
                for (int m = 1; m < 64; m <<= 1) sacc += __shfl_xor(sacc, m, 64);
                if (l == 0) aLs[tp] = sacc + bVdt;
            }
        }
        __syncthreads();
        {
            float acc = 0.f;
            for (int tp = 0; tp < 96; ++tp)
                acc += aLs[tp] * bs2f(mid[(b * 96 + tp) * 256 + tid]);
            ctxL[tid] = acc;
        }
        __syncthreads();
        {   // gates: wave g computes gate g; lanes split the ctx-dot
            int g = tid >> 6, k = tid & 63;
            float part = 0.f;
#pragma unroll
            for (int e = 0; e < 4; ++e) {
                int u = k + e * 64;
                part += bs2f(wp.wihd[g * 257 + u]) * ctxL[u];
            }
#pragma unroll
            for (int m = 1; m < 64; m <<= 1) part += __shfl_xor(part, m, 64);
            if (k == 0)
                gL[g] = part + bs2f(wp.bihd[g]) + bs2f(wp.bhhd[g])
                      + bs2f(wp.whhd[g]) * hi + bs2f(wp.wihd[g * 257 + 256]) * prev;
        }
        __syncthreads();
        if (tid == 0) {
            float c2 = sigm(gL[1]) * ci + sigm(gL[0]) * ftanh(gL[2]);
            float h2 = sigm(gL[3]) * ftanh(c2);
            st[0] = h2; st[1] = c2; st[2] = h2;
            long oi = b * 16 + s;
            if (bf) ((ushort_t*)out)[oi] = f2bs(h2);
            else    ((float*)out)[oi] = h2;
        }
        __syncthreads();
    }
}

// ---------------------------------------------------------------------------
extern "C" void kernel_launch(void* const* d_in, const int* in_sizes, int n_in,
                              void* d_out, int out_size, void* d_ws, size_t ws_size,
                              hipStream_t stream)
{
    const long MT = 1024L * 96;   // 98304 rows

    int* flagp = (int*)d_ws;
    ushort_t* base = (ushort_t*)((char*)d_ws + 256);

    SrcPtrs sp;
    for (int i = 0; i < 26; ++i) sp.p[i] = d_in[i];

    static const long sizes[23] = {
        320, 10, 120, 24, 15, 65536, 256, 131072, 256, 1,
        262144, 262144, 1024, 1024, 65536, 256, 512, 256, 1,
        1028, 4, 4, 4
    };
    ushort_t* ptrs[23];
    long off = 0;
    for (int i = 0; i < 23; ++i) {
        ptrs[i] = base + off;
        off += (sizes[i] + 7) & ~7L;   // 16B-aligned layout
    }

    WsPtrs wp;
    wp.wcfg = ptrs[0];  wp.bcfg = ptrs[1];  wp.eh   = ptrs[2];  wp.ew   = ptrs[3];
    wp.es   = ptrs[4];  wp.wis  = ptrs[5];  wp.bis  = ptrs[6];  wp.wes  = ptrs[7];
    wp.vds  = ptrs[8];  wp.bvds = ptrs[9];  wp.whh  = ptrs[10]; wp.wih  = ptrs[11];
    wp.bih  = ptrs[12]; wp.bhh  = ptrs[13]; wp.wdt  = ptrs[14]; wp.bdt  = ptrs[15];
    wp.wd2t = ptrs[16]; wp.vdt  = ptrs[17]; wp.bvdt = ptrs[18]; wp.wihd = ptrs[19];
    wp.whhd = ptrs[20]; wp.bihd = ptrs[21]; wp.bhhd = ptrs[22];

    ushort_t* inputs = base + off;            // MT*256
    ushort_t* wib    = inputs + MT * 256;     // MT*256
    ushort_t* midb   = wib + MT * 256;        // MT*256
    ushort_t* wdb    = wib;                   // alias: wi dead after encoder

    k_detect<<<1, 64, 0, stream>>>(d_in[3], flagp);
    k_cvt<<<23, 256, 0, stream>>>(sp, wp, flagp);
    k_permA<<<dim3(128, 2), 256, 0, stream>>>(d_in[9], d_in[8], wp.whh, wp.wih, flagp);
    k_permB<<<64, 256, 0, stream>>>(d_in[18], wp.wes, flagp);
    k_build<<<24576, 256, 0, stream>>>(d_in[0], d_in[1], (const int*)d_in[2],
                                       wp, flagp, inputs);
    k_gemm<<<dim3(768, 2), 256, 0, stream>>>(inputs, wp.wis, wp.bis, wib);
    k_encoder<<<64, 1024, 0, stream>>>(wib, inputs, wp, midb);
    k_gemm<<<dim3(768, 2), 256, 0, stream>>>(midb, wp.wdt, wp.bdt, wdb);
    k_decoder<<<1024, 256, 0, stream>>>(midb, wdb, wp, flagp, d_out);
}